// Round 3
// baseline (140.434 us; speedup 1.0000x reference)
//
#include <hip/hip_runtime.h>
#include <stdint.h>

#define MIN_NORM 1e-15f
#define MARGIN 9.0f
#define DIM 64
#define B_ROWS 1024
#define NC 1024
#define N_ENT 200000

__device__ inline float wave_reduce_sum(float v) {
    #pragma unroll
    for (int off = 32; off > 0; off >>= 1) v += __shfl_xor(v, off, 64);
    return v;
}

__device__ inline uint32_t f2bf_bits(float x) {   // RNE fp32 -> bf16 bits
    uint32_t u = __float_as_uint(x);
    return (u + 0x7fffu + ((u >> 16) & 1u)) >> 16;
}
__device__ inline float bfbits2f(uint32_t b) { return __uint_as_float(b << 16); }

// ---------------- head pipeline: one wave per output row ----------------
__global__ __launch_bounds__(256) void head_kernel(
    const int* __restrict__ u_idx, const int* __restrict__ r_idx,
    const float* __restrict__ emb, const float* __restrict__ rel_diag,
    const float* __restrict__ rb1, const float* __restrict__ rb2,
    const float* __restrict__ bias_head, const float* __restrict__ sigma,
    float* __restrict__ head_out, float* __restrict__ scal_out)
{
    const int lane = threadIdx.x & 63;
    const int row = blockIdx.x * 4 + (threadIdx.x >> 6);
    if (row >= B_ROWS) return;
    const int u = u_idx[row];
    const int r = r_idx[row];

    float x = emb[(long)u * DIM + lane];
    {
        float n2 = wave_reduce_sum(x * x);
        float un = fmaxf(sqrtf(n2), MIN_NORM);
        x = tanhf(un) / un * x;
    }
    float y = rb1[(long)r * DIM + lane];
    {
        float n2 = wave_reduce_sum(y * y);
        float un = fmaxf(sqrtf(n2), MIN_NORM);
        y = tanhf(un) / un * y;
    }
    {
        float x2 = wave_reduce_sum(x * x);
        float y2 = wave_reduce_sum(y * y);
        float xy = wave_reduce_sum(x * y);
        float den = 1.0f + 2.0f * xy + x2 * y2;
        x = ((1.0f + 2.0f * xy + y2) * x + (1.0f - x2) * y) / fmaxf(den, MIN_NORM);
    }
    {
        float g  = rel_diag[(long)r * DIM + lane];
        float go = __shfl_xor(g, 1, 64);
        float xo = __shfl_xor(x, 1, 64);
        float gn = fmaxf(sqrtf(g * g + go * go), MIN_NORM);
        x = ((lane & 1) ? (g * xo + go * x) : (g * x - go * xo)) / gn;
    }
    float z = rb2[(long)r * DIM + lane];
    {
        float n2 = wave_reduce_sum(z * z);
        float un = fmaxf(sqrtf(n2), MIN_NORM);
        z = tanhf(un) / un * z;
    }
    {
        float x2 = wave_reduce_sum(x * x);
        float y2 = wave_reduce_sum(z * z);
        float xy = wave_reduce_sum(x * z);
        float den = 1.0f + 2.0f * xy + x2 * y2;
        x = ((1.0f + 2.0f * xy + y2) * x + (1.0f - x2) * z) / fmaxf(den, MIN_NORM);
    }
    float h2 = wave_reduce_sum(x * x);
    head_out[(long)row * DIM + lane] = x;
    if (lane == 0) {
        scal_out[row * 4 + 0] = h2;
        scal_out[row * 4 + 1] = logf(fmaxf(1.0f - h2, MIN_NORM));
        scal_out[row * 4 + 2] = 1.0f / (1.0f + expf(-sigma[r]));
        scal_out[row * 4 + 3] = bias_head[u];
    }
}

// ------- streaming pass: emb -> bf16 pre-transformed tails + scalars -------
// 4-lane group per entity row. tau row = 32 uints (64 bf16, 128 B).
// escal[v] = {|tau|^2, log(max(1-|tau|^2,MIN)), bias_tail[v], 0}
__global__ __launch_bounds__(256) void convert_kernel(
    const float* __restrict__ emb, const float* __restrict__ bias_tail,
    uint32_t* __restrict__ tau, float4* __restrict__ escal)
{
    const int t = threadIdx.x;
    const int g = t >> 2, sub = t & 3;
    const long row = (long)blockIdx.x * 64 + g;
    if (row >= N_ENT) return;

    const float4* p = (const float4*)(emb + row * DIM);
    float4 c[4];
    #pragma unroll
    for (int k = 0; k < 4; ++k) c[k] = p[sub + 4 * k];

    float n2 = 0.0f;
    #pragma unroll
    for (int k = 0; k < 4; ++k) {
        n2 = fmaf(c[k].x, c[k].x, n2); n2 = fmaf(c[k].y, c[k].y, n2);
        n2 = fmaf(c[k].z, c[k].z, n2); n2 = fmaf(c[k].w, c[k].w, n2);
    }
    n2 += __shfl_xor(n2, 1, 64); n2 += __shfl_xor(n2, 2, 64);
    const float un = fmaxf(sqrtf(n2), MIN_NORM);
    const float s = tanhf(un) / un;

    float t2 = 0.0f;
    uint32_t* trow = tau + row * 32;
    #pragma unroll
    for (int k = 0; k < 4; ++k) {
        const int ci = sub + 4 * k;     // fp32 chunk index: elems 4ci..4ci+3
        uint32_t b0 = f2bf_bits(s * c[k].x), b1 = f2bf_bits(s * c[k].y);
        uint32_t b2 = f2bf_bits(s * c[k].z), b3 = f2bf_bits(s * c[k].w);
        float r0 = bfbits2f(b0), r1 = bfbits2f(b1), r2 = bfbits2f(b2), r3 = bfbits2f(b3);
        t2 = fmaf(r0, r0, t2); t2 = fmaf(r1, r1, t2);
        t2 = fmaf(r2, r2, t2); t2 = fmaf(r3, r3, t2);
        uint2 packed = make_uint2(b0 | (b1 << 16), b2 | (b3 << 16));
        ((uint2*)trow)[ci] = packed;    // uints 2ci, 2ci+1
    }
    t2 += __shfl_xor(t2, 1, 64); t2 += __shfl_xor(t2, 2, 64);
    if (sub == 0) {
        float lt = logf(fmaxf(1.0f - t2, MIN_NORM));
        escal[row] = make_float4(t2, lt, bias_tail[row], 0.0f);
    }
}

// ---------------- hot gather: bf16 tails, 4-lane group per candidate ----------------
__global__ __launch_bounds__(256) void score_bf16_kernel(
    const int* __restrict__ v_idx, const uint32_t* __restrict__ tau,
    const float4* __restrict__ escal,
    const float* __restrict__ head, const float* __restrict__ scal,
    float* __restrict__ out)
{
    const int b = blockIdx.y;
    const int base = blockIdx.x * 256;
    const int t = threadIdx.x;
    const int g = t >> 2, sub = t & 3;

    __shared__ float4 sh[DIM / 4];
    __shared__ float ss[4];
    if (t < DIM / 4) sh[t] = ((const float4*)(head + (long)b * DIM))[t];
    if (t < 4) ss[t] = scal[b * 4 + t];

    const int4 v4 = ((const int4*)(v_idx + (long)b * NC + base))[g];
    const int vv[4] = {v4.x, v4.y, v4.z, v4.w};

    __syncthreads();

    // head fragment for this lane: elems [8sub..8sub+8) and [32+8sub..+8)
    const float4 hA = sh[2 * sub], hB = sh[2 * sub + 1];
    const float4 hC = sh[8 + 2 * sub], hD = sh[9 + 2 * sub];

    // gather: per candidate, lane sub loads uint4 at uint-offsets 4sub and 16+4sub
    uint4 q0[4], q1[4];
    #pragma unroll
    for (int j = 0; j < 4; ++j) {
        const uint32_t* r = tau + (long)vv[j] * 32;
        q0[j] = ((const uint4*)r)[sub];
        q1[j] = ((const uint4*)r)[4 + sub];
    }

    float dot[4];
    #pragma unroll
    for (int j = 0; j < 4; ++j) {
        float d = 0.0f;
        uint4 a = q0[j], bq = q1[j];
        d = fmaf(hA.x, bfbits2f(a.x & 0xffffu), d);
        d = fmaf(hA.y, bfbits2f(a.x >> 16), d);
        d = fmaf(hA.z, bfbits2f(a.y & 0xffffu), d);
        d = fmaf(hA.w, bfbits2f(a.y >> 16), d);
        d = fmaf(hB.x, bfbits2f(a.z & 0xffffu), d);
        d = fmaf(hB.y, bfbits2f(a.z >> 16), d);
        d = fmaf(hB.z, bfbits2f(a.w & 0xffffu), d);
        d = fmaf(hB.w, bfbits2f(a.w >> 16), d);
        d = fmaf(hC.x, bfbits2f(bq.x & 0xffffu), d);
        d = fmaf(hC.y, bfbits2f(bq.x >> 16), d);
        d = fmaf(hC.z, bfbits2f(bq.y & 0xffffu), d);
        d = fmaf(hC.w, bfbits2f(bq.y >> 16), d);
        d = fmaf(hD.x, bfbits2f(bq.z & 0xffffu), d);
        d = fmaf(hD.y, bfbits2f(bq.z >> 16), d);
        d = fmaf(hD.z, bfbits2f(bq.w & 0xffffu), d);
        d = fmaf(hD.w, bfbits2f(bq.w >> 16), d);
        d += __shfl_xor(d, 1, 64);
        d += __shfl_xor(d, 2, 64);
        dot[j] = d;
    }

    const float D = (sub == 0) ? dot[0] : (sub == 1) ? dot[1] : (sub == 2) ? dot[2] : dot[3];
    const int myv = vv[sub];
    const float4 es = escal[myv];               // {t2, lt, bt, 0}

    const float h2 = ss[0], ldh = ss[1], sig = ss[2], bh = ss[3];
    const float num = h2 + es.x - 2.0f * D;     // exact |head - tau|^2
    const float dist = logf(fmaxf(num, MIN_NORM))
                     - sig * es.y - (1.0f - sig) * ldh;
    out[(long)b * NC + base + t] = MARGIN - dist + bh + es.z;
}

// ---------------- fallback fp32 path (round-2), used if ws too small ----------------
__global__ __launch_bounds__(256) void score_fp32_kernel(
    const int* __restrict__ v_idx, const float* __restrict__ emb,
    const float* __restrict__ bias_tail,
    const float* __restrict__ head, const float* __restrict__ scal,
    float* __restrict__ out)
{
    const int b = blockIdx.y;
    const int base = blockIdx.x * 256;
    const int t = threadIdx.x;
    const int g = t >> 2, sub = t & 3;

    __shared__ float4 sh[DIM / 4];
    __shared__ float ss[4];
    if (t < DIM / 4) sh[t] = ((const float4*)(head + (long)b * DIM))[t];
    if (t < 4) ss[t] = scal[b * 4 + t];

    const int4 v4 = ((const int4*)(v_idx + (long)b * NC + base))[g];
    const int v0 = v4.x, v1 = v4.y, v2 = v4.z, v3 = v4.w;
    __syncthreads();

    float4 h[4];
    #pragma unroll
    for (int k = 0; k < 4; ++k) h[k] = sh[4 * k + sub];

    float4 e[4][4];
    {
        const float4* p0 = (const float4*)(emb + (long)v0 * DIM);
        const float4* p1 = (const float4*)(emb + (long)v1 * DIM);
        const float4* p2 = (const float4*)(emb + (long)v2 * DIM);
        const float4* p3 = (const float4*)(emb + (long)v3 * DIM);
        #pragma unroll
        for (int k = 0; k < 4; ++k) {
            e[0][k] = p0[4 * k + sub];
            e[1][k] = p1[4 * k + sub];
            e[2][k] = p2[4 * k + sub];
            e[3][k] = p3[4 * k + sub];
        }
    }

    float dot[4], e2[4];
    #pragma unroll
    for (int j = 0; j < 4; ++j) {
        float d = 0.0f, q = 0.0f;
        #pragma unroll
        for (int k = 0; k < 4; ++k) {
            float4 ee = e[j][k]; float4 hh = h[k];
            d = fmaf(hh.x, ee.x, d); d = fmaf(hh.y, ee.y, d);
            d = fmaf(hh.z, ee.z, d); d = fmaf(hh.w, ee.w, d);
            q = fmaf(ee.x, ee.x, q); q = fmaf(ee.y, ee.y, q);
            q = fmaf(ee.z, ee.z, q); q = fmaf(ee.w, ee.w, q);
        }
        d += __shfl_xor(d, 1, 64); d += __shfl_xor(d, 2, 64);
        q += __shfl_xor(q, 1, 64); q += __shfl_xor(q, 2, 64);
        dot[j] = d; e2[j] = q;
    }

    const float D  = (sub == 0) ? dot[0] : (sub == 1) ? dot[1] : (sub == 2) ? dot[2] : dot[3];
    const float E  = (sub == 0) ? e2[0]  : (sub == 1) ? e2[1]  : (sub == 2) ? e2[2]  : e2[3];
    const int myv  = (sub == 0) ? v0     : (sub == 1) ? v1     : (sub == 2) ? v2     : v3;

    const float h2 = ss[0], ldh = ss[1], sig = ss[2], bh = ss[3];
    const float un = fmaxf(sqrtf(E), MIN_NORM);
    const float tn = tanhf(un);
    const float s = tn / un;
    const float t2 = tn * tn;
    const float num = h2 + t2 - 2.0f * s * D;
    const float dist = logf(fmaxf(num, MIN_NORM))
                     - sig * logf(fmaxf(1.0f - t2, MIN_NORM))
                     - (1.0f - sig) * ldh;
    out[(long)b * NC + base + t] = MARGIN - dist + bh + bias_tail[myv];
}

extern "C" void kernel_launch(void* const* d_in, const int* in_sizes, int n_in,
                              void* d_out, int out_size, void* d_ws, size_t ws_size,
                              hipStream_t stream) {
    const int*   u_idx     = (const int*)d_in[0];
    const int*   r_idx     = (const int*)d_in[1];
    const int*   v_idx     = (const int*)d_in[2];
    const float* emb       = (const float*)d_in[3];
    const float* rel_diag  = (const float*)d_in[4];
    const float* rb1       = (const float*)d_in[5];
    const float* rb2       = (const float*)d_in[6];
    const float* bias_head = (const float*)d_in[7];
    const float* bias_tail = (const float*)d_in[8];
    const float* sigma     = (const float*)d_in[9];

    char* ws = (char*)d_ws;
    float*    head  = (float*)ws;                                   // 256 KB
    float*    scal  = (float*)(ws + 262144);                        // 16 KB
    uint32_t* tau   = (uint32_t*)(ws + 278528);                     // 25.6 MB
    float4*   escal = (float4*)(ws + 278528 + (size_t)N_ENT * 128); // 3.2 MB
    const size_t need = 278528 + (size_t)N_ENT * 128 + (size_t)N_ENT * 16;

    head_kernel<<<B_ROWS / 4, 256, 0, stream>>>(
        u_idx, r_idx, emb, rel_diag, rb1, rb2, bias_head, sigma, head, scal);

    if (ws_size >= need) {
        convert_kernel<<<(N_ENT + 63) / 64, 256, 0, stream>>>(emb, bias_tail, tau, escal);
        score_bf16_kernel<<<dim3(NC / 256, B_ROWS), 256, 0, stream>>>(
            v_idx, tau, escal, head, scal, (float*)d_out);
    } else {
        score_fp32_kernel<<<dim3(NC / 256, B_ROWS), 256, 0, stream>>>(
            v_idx, emb, bias_tail, head, scal, (float*)d_out);
    }
}

// Round 4
// 134.923 us; speedup vs baseline: 1.0408x; 1.0408x over previous
//
#include <hip/hip_runtime.h>
#include <stdint.h>

#define MIN_NORM 1e-15f
#define MARGIN 9.0f
#define DIM 64
#define B_ROWS 1024
#define NC 1024
#define N_ENT 200000
#define FP8_SCALE 512.0f
#define FP8_INV_SCALE (1.0f / 512.0f)

typedef float v2f __attribute__((ext_vector_type(2)));

__device__ inline float wave_reduce_sum(float v) {
    #pragma unroll
    for (int off = 32; off > 0; off >>= 1) v += __shfl_xor(v, off, 64);
    return v;
}

// ---------------- head pipeline: one wave per output row ----------------
__global__ __launch_bounds__(256) void head_kernel(
    const int* __restrict__ u_idx, const int* __restrict__ r_idx,
    const float* __restrict__ emb, const float* __restrict__ rel_diag,
    const float* __restrict__ rb1, const float* __restrict__ rb2,
    const float* __restrict__ bias_head, const float* __restrict__ sigma,
    float* __restrict__ head_out, float* __restrict__ scal_out)
{
    const int lane = threadIdx.x & 63;
    const int row = blockIdx.x * 4 + (threadIdx.x >> 6);
    if (row >= B_ROWS) return;
    const int u = u_idx[row];
    const int r = r_idx[row];

    float x = emb[(long)u * DIM + lane];
    {
        float n2 = wave_reduce_sum(x * x);
        float un = fmaxf(sqrtf(n2), MIN_NORM);
        x = tanhf(un) / un * x;
    }
    float y = rb1[(long)r * DIM + lane];
    {
        float n2 = wave_reduce_sum(y * y);
        float un = fmaxf(sqrtf(n2), MIN_NORM);
        y = tanhf(un) / un * y;
    }
    {
        float x2 = wave_reduce_sum(x * x);
        float y2 = wave_reduce_sum(y * y);
        float xy = wave_reduce_sum(x * y);
        float den = 1.0f + 2.0f * xy + x2 * y2;
        x = ((1.0f + 2.0f * xy + y2) * x + (1.0f - x2) * y) / fmaxf(den, MIN_NORM);
    }
    {
        float g  = rel_diag[(long)r * DIM + lane];
        float go = __shfl_xor(g, 1, 64);
        float xo = __shfl_xor(x, 1, 64);
        float gn = fmaxf(sqrtf(g * g + go * go), MIN_NORM);
        x = ((lane & 1) ? (g * xo + go * x) : (g * x - go * xo)) / gn;
    }
    float z = rb2[(long)r * DIM + lane];
    {
        float n2 = wave_reduce_sum(z * z);
        float un = fmaxf(sqrtf(n2), MIN_NORM);
        z = tanhf(un) / un * z;
    }
    {
        float x2 = wave_reduce_sum(x * x);
        float y2 = wave_reduce_sum(z * z);
        float xy = wave_reduce_sum(x * z);
        float den = 1.0f + 2.0f * xy + x2 * y2;
        x = ((1.0f + 2.0f * xy + y2) * x + (1.0f - x2) * z) / fmaxf(den, MIN_NORM);
    }
    float h2 = wave_reduce_sum(x * x);
    head_out[(long)row * DIM + lane] = x;
    if (lane == 0) {
        scal_out[row * 4 + 0] = h2;
        scal_out[row * 4 + 1] = logf(fmaxf(1.0f - h2, MIN_NORM));
        scal_out[row * 4 + 2] = 1.0f / (1.0f + expf(-sigma[r]));
        scal_out[row * 4 + 3] = bias_head[u];
    }
}

// ------- streaming pass: emb -> fp8(e4m3, x512) pre-transformed tails -------
// 4-lane group per entity row. tau row = 64 fp8 = 64 B; lane sub owns
// elements {4sub..4sub+3} + 16k offsets, packed as one uint4.
// escal[v] = {|q/S|^2 (exact), log(max(1-|q/S|^2,MIN)), bias_tail[v], 0}
__global__ __launch_bounds__(256) void convert_kernel(
    const float* __restrict__ emb, const float* __restrict__ bias_tail,
    uint32_t* __restrict__ tau, float4* __restrict__ escal)
{
    const int t = threadIdx.x;
    const int g = t >> 2, sub = t & 3;
    const long row = (long)blockIdx.x * 64 + g;
    if (row >= N_ENT) return;

    const float4* p = (const float4*)(emb + row * DIM);
    float4 c[4];
    #pragma unroll
    for (int k = 0; k < 4; ++k) c[k] = p[sub + 4 * k];

    float n2 = 0.0f;
    #pragma unroll
    for (int k = 0; k < 4; ++k) {
        n2 = fmaf(c[k].x, c[k].x, n2); n2 = fmaf(c[k].y, c[k].y, n2);
        n2 = fmaf(c[k].z, c[k].z, n2); n2 = fmaf(c[k].w, c[k].w, n2);
    }
    n2 += __shfl_xor(n2, 1, 64); n2 += __shfl_xor(n2, 2, 64);
    const float un = fmaxf(sqrtf(n2), MIN_NORM);
    const float s = tanhf(un) / un * FP8_SCALE;

    float t2 = 0.0f;   // exact |q|^2 of the QUANTIZED (descaled) row
    uint32_t pk[4];
    #pragma unroll
    for (int k = 0; k < 4; ++k) {
        uint32_t u = __builtin_amdgcn_cvt_pk_fp8_f32(s * c[k].x, s * c[k].y, 0, false);
        u = __builtin_amdgcn_cvt_pk_fp8_f32(s * c[k].z, s * c[k].w, u, true);
        pk[k] = u;
        v2f lo = __builtin_amdgcn_cvt_pk_f32_fp8(u, false);
        v2f hi = __builtin_amdgcn_cvt_pk_f32_fp8(u, true);
        t2 = fmaf(lo.x, lo.x, t2); t2 = fmaf(lo.y, lo.y, t2);
        t2 = fmaf(hi.x, hi.x, t2); t2 = fmaf(hi.y, hi.y, t2);
    }
    uint32_t* trow = tau + row * 16;           // 16 uints = 64 B
    ((uint4*)trow)[sub] = make_uint4(pk[0], pk[1], pk[2], pk[3]);

    t2 *= FP8_INV_SCALE * FP8_INV_SCALE;
    t2 += __shfl_xor(t2, 1, 64); t2 += __shfl_xor(t2, 2, 64);
    if (sub == 0) {
        float lt = logf(fmaxf(1.0f - t2, MIN_NORM));
        escal[row] = make_float4(t2, lt, bias_tail[row], 0.0f);
    }
}

// ---------------- hot gather: fp8 tails, 4-lane group per candidate ----------------
__global__ __launch_bounds__(256) void score_fp8_kernel(
    const int* __restrict__ v_idx, const uint32_t* __restrict__ tau,
    const float4* __restrict__ escal,
    const float* __restrict__ head, const float* __restrict__ scal,
    float* __restrict__ out)
{
    const int b = blockIdx.y;
    const int base = blockIdx.x * 256;
    const int t = threadIdx.x;
    const int g = t >> 2, sub = t & 3;

    __shared__ float4 sh[DIM / 4];
    __shared__ float ss[4];
    if (t < DIM / 4) sh[t] = ((const float4*)(head + (long)b * DIM))[t];
    if (t < 4) ss[t] = scal[b * 4 + t];

    const int4 v4 = ((const int4*)(v_idx + (long)b * NC + base))[g];
    const int vv[4] = {v4.x, v4.y, v4.z, v4.w};

    __syncthreads();

    // head fragments for lane sub's element set, pre-scaled by 1/S
    float4 h[4];
    #pragma unroll
    for (int k = 0; k < 4; ++k) {
        float4 v = sh[4 * k + sub];
        h[k] = make_float4(v.x * FP8_INV_SCALE, v.y * FP8_INV_SCALE,
                           v.z * FP8_INV_SCALE, v.w * FP8_INV_SCALE);
    }

    // one uint4 (16 fp8) load per candidate per lane — full row per group
    uint4 q[4];
    #pragma unroll
    for (int j = 0; j < 4; ++j)
        q[j] = ((const uint4*)(tau + (long)vv[j] * 16))[sub];

    float dot[4];
    #pragma unroll
    for (int j = 0; j < 4; ++j) {
        float d = 0.0f;
        const uint32_t w[4] = {q[j].x, q[j].y, q[j].z, q[j].w};
        #pragma unroll
        for (int k = 0; k < 4; ++k) {
            v2f lo = __builtin_amdgcn_cvt_pk_f32_fp8(w[k], false);
            v2f hi = __builtin_amdgcn_cvt_pk_f32_fp8(w[k], true);
            d = fmaf(h[k].x, lo.x, d);
            d = fmaf(h[k].y, lo.y, d);
            d = fmaf(h[k].z, hi.x, d);
            d = fmaf(h[k].w, hi.y, d);
        }
        d += __shfl_xor(d, 1, 64);
        d += __shfl_xor(d, 2, 64);
        dot[j] = d;
    }

    const float D = (sub == 0) ? dot[0] : (sub == 1) ? dot[1] : (sub == 2) ? dot[2] : dot[3];
    const int myv = vv[sub];
    const float4 es = escal[myv];               // {t2, lt, bt, 0}

    const float h2 = ss[0], ldh = ss[1], sig = ss[2], bh = ss[3];
    const float num = h2 + es.x - 2.0f * D;     // exact |head - q|^2
    const float dist = logf(fmaxf(num, MIN_NORM))
                     - sig * es.y - (1.0f - sig) * ldh;
    out[(long)b * NC + base + t] = MARGIN - dist + bh + es.z;
}

// ---------------- fallback fp32 path, used only if ws too small ----------------
__global__ __launch_bounds__(256) void score_fp32_kernel(
    const int* __restrict__ v_idx, const float* __restrict__ emb,
    const float* __restrict__ bias_tail,
    const float* __restrict__ head, const float* __restrict__ scal,
    float* __restrict__ out)
{
    const int b = blockIdx.y;
    const int base = blockIdx.x * 256;
    const int t = threadIdx.x;
    const int g = t >> 2, sub = t & 3;

    __shared__ float4 sh[DIM / 4];
    __shared__ float ss[4];
    if (t < DIM / 4) sh[t] = ((const float4*)(head + (long)b * DIM))[t];
    if (t < 4) ss[t] = scal[b * 4 + t];

    const int4 v4 = ((const int4*)(v_idx + (long)b * NC + base))[g];
    const int v0 = v4.x, v1 = v4.y, v2 = v4.z, v3 = v4.w;
    __syncthreads();

    float4 h[4];
    #pragma unroll
    for (int k = 0; k < 4; ++k) h[k] = sh[4 * k + sub];

    float4 e[4][4];
    {
        const float4* p0 = (const float4*)(emb + (long)v0 * DIM);
        const float4* p1 = (const float4*)(emb + (long)v1 * DIM);
        const float4* p2 = (const float4*)(emb + (long)v2 * DIM);
        const float4* p3 = (const float4*)(emb + (long)v3 * DIM);
        #pragma unroll
        for (int k = 0; k < 4; ++k) {
            e[0][k] = p0[4 * k + sub];
            e[1][k] = p1[4 * k + sub];
            e[2][k] = p2[4 * k + sub];
            e[3][k] = p3[4 * k + sub];
        }
    }

    float dot[4], e2[4];
    #pragma unroll
    for (int j = 0; j < 4; ++j) {
        float d = 0.0f, qq = 0.0f;
        #pragma unroll
        for (int k = 0; k < 4; ++k) {
            float4 ee = e[j][k]; float4 hh = h[k];
            d = fmaf(hh.x, ee.x, d); d = fmaf(hh.y, ee.y, d);
            d = fmaf(hh.z, ee.z, d); d = fmaf(hh.w, ee.w, d);
            qq = fmaf(ee.x, ee.x, qq); qq = fmaf(ee.y, ee.y, qq);
            qq = fmaf(ee.z, ee.z, qq); qq = fmaf(ee.w, ee.w, qq);
        }
        d += __shfl_xor(d, 1, 64); d += __shfl_xor(d, 2, 64);
        qq += __shfl_xor(qq, 1, 64); qq += __shfl_xor(qq, 2, 64);
        dot[j] = d; e2[j] = qq;
    }

    const float D  = (sub == 0) ? dot[0] : (sub == 1) ? dot[1] : (sub == 2) ? dot[2] : dot[3];
    const float E  = (sub == 0) ? e2[0]  : (sub == 1) ? e2[1]  : (sub == 2) ? e2[2]  : e2[3];
    const int myv  = (sub == 0) ? v0     : (sub == 1) ? v1     : (sub == 2) ? v2     : v3;

    const float h2 = ss[0], ldh = ss[1], sig = ss[2], bh = ss[3];
    const float un = fmaxf(sqrtf(E), MIN_NORM);
    const float tn = tanhf(un);
    const float s = tn / un;
    const float t2 = tn * tn;
    const float num = h2 + t2 - 2.0f * s * D;
    const float dist = logf(fmaxf(num, MIN_NORM))
                     - sig * logf(fmaxf(1.0f - t2, MIN_NORM))
                     - (1.0f - sig) * ldh;
    out[(long)b * NC + base + t] = MARGIN - dist + bh + bias_tail[myv];
}

extern "C" void kernel_launch(void* const* d_in, const int* in_sizes, int n_in,
                              void* d_out, int out_size, void* d_ws, size_t ws_size,
                              hipStream_t stream) {
    const int*   u_idx     = (const int*)d_in[0];
    const int*   r_idx     = (const int*)d_in[1];
    const int*   v_idx     = (const int*)d_in[2];
    const float* emb       = (const float*)d_in[3];
    const float* rel_diag  = (const float*)d_in[4];
    const float* rb1       = (const float*)d_in[5];
    const float* rb2       = (const float*)d_in[6];
    const float* bias_head = (const float*)d_in[7];
    const float* bias_tail = (const float*)d_in[8];
    const float* sigma     = (const float*)d_in[9];

    char* ws = (char*)d_ws;
    float*    head  = (float*)ws;                                  // 256 KB
    float*    scal  = (float*)(ws + 262144);                       // 16 KB
    uint32_t* tau   = (uint32_t*)(ws + 278528);                    // 12.8 MB fp8
    float4*   escal = (float4*)(ws + 278528 + (size_t)N_ENT * 64); // 3.2 MB
    const size_t need = 278528 + (size_t)N_ENT * 64 + (size_t)N_ENT * 16;

    head_kernel<<<B_ROWS / 4, 256, 0, stream>>>(
        u_idx, r_idx, emb, rel_diag, rb1, rb2, bias_head, sigma, head, scal);

    if (ws_size >= need) {
        convert_kernel<<<(N_ENT + 63) / 64, 256, 0, stream>>>(emb, bias_tail, tau, escal);
        score_fp8_kernel<<<dim3(NC / 256, B_ROWS), 256, 0, stream>>>(
            v_idx, tau, escal, head, scal, (float*)d_out);
    } else {
        score_fp32_kernel<<<dim3(NC / 256, B_ROWS), 256, 0, stream>>>(
            v_idx, emb, bias_tail, head, scal, (float*)d_out);
    }
}

// Round 6
// 124.916 us; speedup vs baseline: 1.1242x; 1.0801x over previous
//
#include <hip/hip_runtime.h>
#include <stdint.h>

#define MIN_NORM 1e-15f
#define MARGIN 9.0f
#define DIM 64
#define B_ROWS 1024
#define NC 1024
#define N_ENT 200000
#define FP8_SCALE 512.0f
#define FP8_INV_SCALE (1.0f / 512.0f)
#define CONV_BLOCKS ((N_ENT + 63) / 64)   // 3125
#define HEAD_BLOCKS (B_ROWS / 4)          // 256

typedef float v2f __attribute__((ext_vector_type(2)));

__device__ inline float wave_reduce_sum(float v) {
    #pragma unroll
    for (int off = 32; off > 0; off >>= 1) v += __shfl_xor(v, off, 64);
    return v;
}

// ---------------- head pipeline body: one wave per output row ----------------
__device__ inline void head_body(
    int row,
    const int* __restrict__ u_idx, const int* __restrict__ r_idx,
    const float* __restrict__ emb, const float* __restrict__ rel_diag,
    const float* __restrict__ rb1, const float* __restrict__ rb2,
    const float* __restrict__ bias_head, const float* __restrict__ sigma,
    float* __restrict__ head_out, float* __restrict__ scal_out)
{
    const int lane = threadIdx.x & 63;
    const int u = u_idx[row];
    const int r = r_idx[row];

    float x = emb[(long)u * DIM + lane];
    {
        float n2 = wave_reduce_sum(x * x);
        float un = fmaxf(sqrtf(n2), MIN_NORM);
        x = tanhf(un) / un * x;
    }
    float y = rb1[(long)r * DIM + lane];
    {
        float n2 = wave_reduce_sum(y * y);
        float un = fmaxf(sqrtf(n2), MIN_NORM);
        y = tanhf(un) / un * y;
    }
    {
        float x2 = wave_reduce_sum(x * x);
        float y2 = wave_reduce_sum(y * y);
        float xy = wave_reduce_sum(x * y);
        float den = 1.0f + 2.0f * xy + x2 * y2;
        x = ((1.0f + 2.0f * xy + y2) * x + (1.0f - x2) * y) / fmaxf(den, MIN_NORM);
    }
    {
        float g  = rel_diag[(long)r * DIM + lane];
        float go = __shfl_xor(g, 1, 64);
        float xo = __shfl_xor(x, 1, 64);
        float gn = fmaxf(sqrtf(g * g + go * go), MIN_NORM);
        x = ((lane & 1) ? (g * xo + go * x) : (g * x - go * xo)) / gn;
    }
    float z = rb2[(long)r * DIM + lane];
    {
        float n2 = wave_reduce_sum(z * z);
        float un = fmaxf(sqrtf(n2), MIN_NORM);
        z = tanhf(un) / un * z;
    }
    {
        float x2 = wave_reduce_sum(x * x);
        float y2 = wave_reduce_sum(z * z);
        float xy = wave_reduce_sum(x * z);
        float den = 1.0f + 2.0f * xy + x2 * y2;
        x = ((1.0f + 2.0f * xy + y2) * x + (1.0f - x2) * z) / fmaxf(den, MIN_NORM);
    }
    float h2 = wave_reduce_sum(x * x);
    head_out[(long)row * DIM + lane] = x;
    if (lane == 0) {
        scal_out[row * 4 + 0] = h2;
        scal_out[row * 4 + 1] = logf(fmaxf(1.0f - h2, MIN_NORM));
        scal_out[row * 4 + 2] = 1.0f / (1.0f + expf(-sigma[r]));
        scal_out[row * 4 + 3] = bias_head[u];
    }
}

// ------- fused: [0, CONV_BLOCKS): emb -> fp8(e4m3, x512) tails (64 B/row)
//                [CONV_BLOCKS, +HEAD_BLOCKS): head pipeline -------
// tau layout: lane sub's uint4 = packed fp32 chunks {sub, sub+4, sub+8, sub+12}
// (chunk = 4 consecutive elements). Score MUST pair with sh[4*k + sub].
__global__ __launch_bounds__(256) void prep_kernel(
    const int* __restrict__ u_idx, const int* __restrict__ r_idx,
    const float* __restrict__ emb, const float* __restrict__ rel_diag,
    const float* __restrict__ rb1, const float* __restrict__ rb2,
    const float* __restrict__ bias_head, const float* __restrict__ sigma,
    uint32_t* __restrict__ tau, float* __restrict__ head_out,
    float* __restrict__ scal_out)
{
    const int t = threadIdx.x;
    if (blockIdx.x >= CONV_BLOCKS) {
        int row = (blockIdx.x - CONV_BLOCKS) * 4 + (t >> 6);
        head_body(row, u_idx, r_idx, emb, rel_diag, rb1, rb2,
                  bias_head, sigma, head_out, scal_out);
        return;
    }
    const int g = t >> 2, sub = t & 3;
    const long row = (long)blockIdx.x * 64 + g;
    if (row >= N_ENT) return;

    const float4* p = (const float4*)(emb + row * DIM);
    float4 c[4];
    #pragma unroll
    for (int k = 0; k < 4; ++k) c[k] = p[sub + 4 * k];

    float n2 = 0.0f;
    #pragma unroll
    for (int k = 0; k < 4; ++k) {
        n2 = fmaf(c[k].x, c[k].x, n2); n2 = fmaf(c[k].y, c[k].y, n2);
        n2 = fmaf(c[k].z, c[k].z, n2); n2 = fmaf(c[k].w, c[k].w, n2);
    }
    n2 += __shfl_xor(n2, 1, 64); n2 += __shfl_xor(n2, 2, 64);
    const float un = fmaxf(sqrtf(n2), MIN_NORM);
    const float s = tanhf(un) / un * FP8_SCALE;

    uint32_t pk[4];
    #pragma unroll
    for (int k = 0; k < 4; ++k) {
        uint32_t u = __builtin_amdgcn_cvt_pk_fp8_f32(s * c[k].x, s * c[k].y, 0, false);
        u = __builtin_amdgcn_cvt_pk_fp8_f32(s * c[k].z, s * c[k].w, u, true);
        pk[k] = u;
    }
    ((uint4*)(tau + row * 16))[sub] = make_uint4(pk[0], pk[1], pk[2], pk[3]);
}

// ---------------- hot gather: fp8 tails, 4-lane group per candidate ----------------
// Single 64 B line per candidate; |q|^2 recomputed in-loop; bias_tail is a
// 4 B gather from the hot 800 KB input table.
__global__ __launch_bounds__(256) void score_fp8_kernel(
    const int* __restrict__ v_idx, const uint32_t* __restrict__ tau,
    const float* __restrict__ bias_tail,
    const float* __restrict__ head, const float* __restrict__ scal,
    float* __restrict__ out)
{
    const int b = blockIdx.y;
    const int base = blockIdx.x * 256;
    const int t = threadIdx.x;
    const int g = t >> 2, sub = t & 3;

    __shared__ float4 sh[DIM / 4];
    __shared__ float ss[4];
    if (t < DIM / 4) sh[t] = ((const float4*)(head + (long)b * DIM))[t];
    if (t < 4) ss[t] = scal[b * 4 + t];

    const int4 v4 = ((const int4*)(v_idx + (long)b * NC + base))[g];
    const int vv[4] = {v4.x, v4.y, v4.z, v4.w};

    // one uint4 (16 fp8) load per candidate per lane — full 64 B row per group
    uint4 q[4];
    #pragma unroll
    for (int j = 0; j < 4; ++j)
        q[j] = ((const uint4*)(tau + (long)vv[j] * 16))[sub];

    __syncthreads();

    // head fragment matching tau layout: chunk (4k + sub), pre-scaled by 1/S
    float4 h[4];
    #pragma unroll
    for (int k = 0; k < 4; ++k) {
        float4 v = sh[4 * k + sub];
        h[k] = make_float4(v.x * FP8_INV_SCALE, v.y * FP8_INV_SCALE,
                           v.z * FP8_INV_SCALE, v.w * FP8_INV_SCALE);
    }

    float dot[4], qq2[4];
    #pragma unroll
    for (int j = 0; j < 4; ++j) {
        float d = 0.0f, qq = 0.0f;
        const uint32_t w[4] = {q[j].x, q[j].y, q[j].z, q[j].w};
        #pragma unroll
        for (int k = 0; k < 4; ++k) {
            v2f lo = __builtin_amdgcn_cvt_pk_f32_fp8(w[k], false);
            v2f hi = __builtin_amdgcn_cvt_pk_f32_fp8(w[k], true);
            d = fmaf(h[k].x, lo.x, d);
            d = fmaf(h[k].y, lo.y, d);
            d = fmaf(h[k].z, hi.x, d);
            d = fmaf(h[k].w, hi.y, d);
            qq = fmaf(lo.x, lo.x, qq); qq = fmaf(lo.y, lo.y, qq);
            qq = fmaf(hi.x, hi.x, qq); qq = fmaf(hi.y, hi.y, qq);
        }
        d += __shfl_xor(d, 1, 64); d += __shfl_xor(d, 2, 64);
        qq += __shfl_xor(qq, 1, 64); qq += __shfl_xor(qq, 2, 64);
        dot[j] = d; qq2[j] = qq;
    }

    const float D  = (sub == 0) ? dot[0] : (sub == 1) ? dot[1] : (sub == 2) ? dot[2] : dot[3];
    const float QQ = (sub == 0) ? qq2[0] : (sub == 1) ? qq2[1] : (sub == 2) ? qq2[2] : qq2[3];
    const int myv  = vv[sub];

    const float h2 = ss[0], ldh = ss[1], sig = ss[2], bh = ss[3];
    const float t2 = QQ * (FP8_INV_SCALE * FP8_INV_SCALE);   // exact |q/S|^2
    const float lt = logf(fmaxf(1.0f - t2, MIN_NORM));
    const float num = h2 + t2 - 2.0f * D;                    // exact |head - q/S|^2
    const float dist = logf(fmaxf(num, MIN_NORM))
                     - sig * lt - (1.0f - sig) * ldh;
    out[(long)b * NC + base + t] = MARGIN - dist + bh + bias_tail[myv];
}

// ---------------- fallback fp32 path, used only if ws too small ----------------
__global__ __launch_bounds__(256) void head_kernel(
    const int* __restrict__ u_idx, const int* __restrict__ r_idx,
    const float* __restrict__ emb, const float* __restrict__ rel_diag,
    const float* __restrict__ rb1, const float* __restrict__ rb2,
    const float* __restrict__ bias_head, const float* __restrict__ sigma,
    float* __restrict__ head_out, float* __restrict__ scal_out)
{
    const int row = blockIdx.x * 4 + (threadIdx.x >> 6);
    if (row >= B_ROWS) return;
    head_body(row, u_idx, r_idx, emb, rel_diag, rb1, rb2,
              bias_head, sigma, head_out, scal_out);
}

__global__ __launch_bounds__(256) void score_fp32_kernel(
    const int* __restrict__ v_idx, const float* __restrict__ emb,
    const float* __restrict__ bias_tail,
    const float* __restrict__ head, const float* __restrict__ scal,
    float* __restrict__ out)
{
    const int b = blockIdx.y;
    const int base = blockIdx.x * 256;
    const int t = threadIdx.x;
    const int g = t >> 2, sub = t & 3;

    __shared__ float4 sh[DIM / 4];
    __shared__ float ss[4];
    if (t < DIM / 4) sh[t] = ((const float4*)(head + (long)b * DIM))[t];
    if (t < 4) ss[t] = scal[b * 4 + t];

    const int4 v4 = ((const int4*)(v_idx + (long)b * NC + base))[g];
    const int v0 = v4.x, v1 = v4.y, v2 = v4.z, v3 = v4.w;
    __syncthreads();

    float4 h[4];
    #pragma unroll
    for (int k = 0; k < 4; ++k) h[k] = sh[4 * k + sub];

    float4 e[4][4];
    {
        const float4* p0 = (const float4*)(emb + (long)v0 * DIM);
        const float4* p1 = (const float4*)(emb + (long)v1 * DIM);
        const float4* p2 = (const float4*)(emb + (long)v2 * DIM);
        const float4* p3 = (const float4*)(emb + (long)v3 * DIM);
        #pragma unroll
        for (int k = 0; k < 4; ++k) {
            e[0][k] = p0[4 * k + sub];
            e[1][k] = p1[4 * k + sub];
            e[2][k] = p2[4 * k + sub];
            e[3][k] = p3[4 * k + sub];
        }
    }

    float dot[4], e2[4];
    #pragma unroll
    for (int j = 0; j < 4; ++j) {
        float d = 0.0f, qq = 0.0f;
        #pragma unroll
        for (int k = 0; k < 4; ++k) {
            float4 ee = e[j][k]; float4 hh = h[k];
            d = fmaf(hh.x, ee.x, d); d = fmaf(hh.y, ee.y, d);
            d = fmaf(hh.z, ee.z, d); d = fmaf(hh.w, ee.w, d);
            qq = fmaf(ee.x, ee.x, qq); qq = fmaf(ee.y, ee.y, qq);
            qq = fmaf(ee.z, ee.z, qq); qq = fmaf(ee.w, ee.w, qq);
        }
        d += __shfl_xor(d, 1, 64); d += __shfl_xor(d, 2, 64);
        qq += __shfl_xor(qq, 1, 64); qq += __shfl_xor(qq, 2, 64);
        dot[j] = d; e2[j] = qq;
    }

    const float D  = (sub == 0) ? dot[0] : (sub == 1) ? dot[1] : (sub == 2) ? dot[2] : dot[3];
    const float E  = (sub == 0) ? e2[0]  : (sub == 1) ? e2[1]  : (sub == 2) ? e2[2]  : e2[3];
    const int myv  = (sub == 0) ? v0     : (sub == 1) ? v1     : (sub == 2) ? v2     : v3;

    const float h2 = ss[0], ldh = ss[1], sig = ss[2], bh = ss[3];
    const float un = fmaxf(sqrtf(E), MIN_NORM);
    const float tn = tanhf(un);
    const float s = tn / un;
    const float t2 = tn * tn;
    const float num = h2 + t2 - 2.0f * s * D;
    const float dist = logf(fmaxf(num, MIN_NORM))
                     - sig * logf(fmaxf(1.0f - t2, MIN_NORM))
                     - (1.0f - sig) * ldh;
    out[(long)b * NC + base + t] = MARGIN - dist + bh + bias_tail[myv];
}

extern "C" void kernel_launch(void* const* d_in, const int* in_sizes, int n_in,
                              void* d_out, int out_size, void* d_ws, size_t ws_size,
                              hipStream_t stream) {
    const int*   u_idx     = (const int*)d_in[0];
    const int*   r_idx     = (const int*)d_in[1];
    const int*   v_idx     = (const int*)d_in[2];
    const float* emb       = (const float*)d_in[3];
    const float* rel_diag  = (const float*)d_in[4];
    const float* rb1       = (const float*)d_in[5];
    const float* rb2       = (const float*)d_in[6];
    const float* bias_head = (const float*)d_in[7];
    const float* bias_tail = (const float*)d_in[8];
    const float* sigma     = (const float*)d_in[9];

    char* ws = (char*)d_ws;
    float*    head = (float*)ws;                 // 256 KB
    float*    scal = (float*)(ws + 262144);      // 16 KB
    uint32_t* tau  = (uint32_t*)(ws + 278528);   // 12.8 MB fp8 tails
    const size_t need = 278528 + (size_t)N_ENT * 64;

    if (ws_size >= need) {
        prep_kernel<<<CONV_BLOCKS + HEAD_BLOCKS, 256, 0, stream>>>(
            u_idx, r_idx, emb, rel_diag, rb1, rb2, bias_head, sigma,
            tau, head, scal);
        score_fp8_kernel<<<dim3(NC / 256, B_ROWS), 256, 0, stream>>>(
            v_idx, tau, bias_tail, head, scal, (float*)d_out);
    } else {
        head_kernel<<<HEAD_BLOCKS, 256, 0, stream>>>(
            u_idx, r_idx, emb, rel_diag, rb1, rb2, bias_head, sigma, head, scal);
        score_fp32_kernel<<<dim3(NC / 256, B_ROWS), 256, 0, stream>>>(
            v_idx, emb, bias_tail, head, scal, (float*)d_out);
    }
}